// Round 15
// baseline (186.274 us; speedup 1.0000x reference)
//
#include <hip/hip_runtime.h>
#include <hip/hip_bf16.h>
#include <math.h>

#define DIM 128
#define NSLOT 8
#define NTOK 4096
#define NB 32
#define ACHUNK 64
#define ANCH (NTOK / ACHUNK)  // 64
#define LN_EPS 1e-3f
#define ATT_EPS 1e-8f
#define SCALE 0.08838834764831845f  // 128^-0.5

#define BM 64
#define LDK 136

typedef short bf16x8 __attribute__((ext_vector_type(8)));
typedef float f32x4 __attribute__((ext_vector_type(4)));
typedef unsigned short ushort8_t __attribute__((ext_vector_type(8)));

__device__ __forceinline__ float bf2f(unsigned short u) {
  return __uint_as_float(((unsigned)u) << 16);
}
__device__ __forceinline__ unsigned short f2bf(float f) {
  unsigned u = __float_as_uint(f);
  unsigned r = (u + 0x7FFFu + ((u >> 16) & 1u)) >> 16;
  return (unsigned short)r;
}

__device__ __forceinline__ float erfinv_like_xla(float x) {
  double xd = (double)x;
  double w = -log1p(-xd * xd);
  double p;
  if (w < 5.0) {
    w = w - 2.5;
    p = 2.81022636e-08;
    p = 3.43273939e-07 + p * w;
    p = -3.5233877e-06 + p * w;
    p = -4.39150654e-06 + p * w;
    p = 0.00021858087 + p * w;
    p = -0.00125372503 + p * w;
    p = -0.00417768164 + p * w;
    p = 0.246640727 + p * w;
    p = 1.50140941 + p * w;
  } else {
    w = sqrt(w) - 3.0;
    p = -0.000200214257;
    p = 0.000100950558 + p * w;
    p = 0.00134934322 + p * w;
    p = -0.00367342844 + p * w;
    p = 0.00573950773 + p * w;
    p = -0.0076224613 + p * w;
    p = 0.00943887047 + p * w;
    p = 1.00167406 + p * w;
    p = 2.83297682 + p * w;
  }
  return (float)(p * xd);
}

// ---------------------------------------------------------------------------
// Kernel 1: per-batch block: threefry slots init + Wk/Wv bf16 cast + q0 tail.
// ---------------------------------------------------------------------------
__global__ __launch_bounds__(256) void k_init_slots(
    const float* __restrict__ mu, const float* __restrict__ lsig,
    float* __restrict__ slots, const float* __restrict__ Wk,
    const float* __restrict__ Wv, unsigned short* __restrict__ Wbf,
    const float* __restrict__ Wq, const float* __restrict__ lnw,
    const float* __restrict__ lnb, unsigned short* __restrict__ qbf) {
  int b = blockIdx.x, t = threadIdx.x;
  __shared__ __align__(16) float sc[NSLOT][DIM];
  __shared__ __align__(16) float sln[NSLOT][DIM];

#pragma unroll
  for (int u = 0; u < 2; ++u) {
    int i = b * 512 + u * 256 + t;
    Wbf[i] = f2bf(Wk[i]);
    Wbf[DIM * DIM + i] = f2bf(Wv[i]);
  }

#pragma unroll
  for (int r4 = 0; r4 < 4; ++r4) {
    int idx = b * 1024 + r4 * 256 + t;
    uint32_t x0 = 0u, x1 = (uint32_t)idx;
    uint32_t k0 = 0u, k1 = 42u;
    uint32_t ks[3] = {k0, k1, k0 ^ k1 ^ 0x1BD11BDAu};
    x0 += ks[0];
    x1 += ks[1];
    const int rot[2][4] = {{13, 15, 26, 6}, {17, 29, 16, 24}};
#pragma unroll
    for (int blk = 0; blk < 5; ++blk) {
      const int* r = rot[blk & 1];
#pragma unroll
      for (int j = 0; j < 4; ++j) {
        x0 += x1;
        x1 = (x1 << r[j]) | (x1 >> (32 - r[j]));
        x1 ^= x0;
      }
      x0 += ks[(blk + 1) % 3];
      x1 += ks[(blk + 2) % 3] + (uint32_t)(blk + 1);
    }
    uint32_t bits = x0 ^ x1;
    float f = __uint_as_float((bits >> 9) | 0x3F800000u) - 1.0f;
    const float mn = __uint_as_float(0xBF7FFFFFu);
    float u = fmaxf(f * 2.0f + mn, mn);
    float noise = 1.41421356f * erfinv_like_xla(u);
    int d = idx & (DIM - 1);
    float val = mu[d] + expf(lsig[d]) * noise;
    slots[idx] = val;
    int li = r4 * 256 + t;
    sc[li >> 7][li & (DIM - 1)] = val;
  }
  __syncthreads();

  {  // LN(slots) -> sln
    int s = t >> 5, c = t & 31;
    float4 xv = *reinterpret_cast<const float4*>(&sc[s][c * 4]);
    float ps = xv.x + xv.y + xv.z + xv.w;
    float pq = xv.x * xv.x + xv.y * xv.y + xv.z * xv.z + xv.w * xv.w;
#pragma unroll
    for (int m = 16; m >= 1; m >>= 1) {
      ps += __shfl_xor(ps, m, 32);
      pq += __shfl_xor(pq, m, 32);
    }
    float mean = ps * (1.0f / DIM);
    float var = fmaxf(pq * (1.0f / DIM) - mean * mean, 0.0f);
    float inv = 1.0f / sqrtf(var + LN_EPS);
    float vals[4] = {xv.x, xv.y, xv.z, xv.w};
#pragma unroll
    for (int ii = 0; ii < 4; ++ii) {
      int d = c * 4 + ii;
      sln[s][d] = (vals[ii] - mean) * inv * lnw[d] + lnb[d];
    }
  }
  __syncthreads();
  {  // q0 = SCALE * sln @ Wq^T
    int s = t >> 5, c = t & 31;
#pragma unroll
    for (int ii = 0; ii < 4; ++ii) {
      int e = c + 32 * ii;
      const float* wr = Wq + e * DIM;
      float acc = 0.0f;
#pragma unroll
      for (int d4 = 0; d4 < DIM / 4; ++d4) {
        float4 w4 = *reinterpret_cast<const float4*>(wr + d4 * 4);
        float4 s4 = *reinterpret_cast<const float4*>(&sln[s][d4 * 4]);
        acc += s4.x * w4.x + s4.y * w4.y + s4.z * w4.z + s4.w * w4.w;
      }
      qbf[(b * NSLOT + s) * DIM + e] = f2bf(SCALE * acc);
    }
  }
}

// ---------------------------------------------------------------------------
// Kernel 2: LN + MFMA projection. 512 threads / 8 waves, BM=64 tokens.
// ---------------------------------------------------------------------------
__global__ __launch_bounds__(512) void k_ln_kv(
    const float* __restrict__ inp, const unsigned short* __restrict__ Wbf,
    const float* __restrict__ lnw, const float* __restrict__ lnb,
    unsigned short* __restrict__ kt, unsigned short* __restrict__ vt) {
  __shared__ __align__(16) unsigned short A[BM * LDK];    // 17408 B
  __shared__ __align__(16) unsigned short Bv[DIM * 72];   // 18432 B
  int t = threadIdx.x;
  int tg = blockIdx.x;

  {  // Phase A: LN 64 rows; 8 threads/row, 16 d each
    int r = t >> 3, p = t & 7;
    const float* src = inp + ((size_t)tg * BM + r) * DIM + p * 16;
    float xr[16];
    float s = 0.f, sq = 0.f;
#pragma unroll
    for (int i4 = 0; i4 < 4; ++i4) {
      float4 v = *reinterpret_cast<const float4*>(src + i4 * 4);
      xr[i4 * 4 + 0] = v.x; xr[i4 * 4 + 1] = v.y;
      xr[i4 * 4 + 2] = v.z; xr[i4 * 4 + 3] = v.w;
      s += v.x + v.y + v.z + v.w;
      sq += v.x * v.x + v.y * v.y + v.z * v.z + v.w * v.w;
    }
    s += __shfl_xor(s, 1); sq += __shfl_xor(sq, 1);
    s += __shfl_xor(s, 2); sq += __shfl_xor(sq, 2);
    s += __shfl_xor(s, 4); sq += __shfl_xor(sq, 4);
    float mean = s * (1.0f / DIM);
    float var = fmaxf(sq * (1.0f / DIM) - mean * mean, 0.0f);
    float inv = 1.0f / sqrtf(var + LN_EPS);
#pragma unroll
    for (int c8 = 0; c8 < 2; ++c8) {
      ushort8_t pk;
#pragma unroll
      for (int j = 0; j < 8; ++j) {
        int d = p * 16 + c8 * 8 + j;
        float y = (xr[c8 * 8 + j] - mean) * inv * lnw[d] + lnb[d];
        pk[j] = f2bf(y);
      }
      *reinterpret_cast<ushort8_t*>(&A[r * LDK + p * 16 + c8 * 8]) = pk;
    }
  }
  __syncthreads();

  int w = t >> 6, l = t & 63, lm = l & 15, lg = l >> 4;
  int mat = w >> 2;
  int ebase = (w & 3) * 32;
  const unsigned short* Wsrc = Wbf + mat * DIM * DIM;

  f32x4 acc[8];
#pragma unroll
  for (int i = 0; i < 8; ++i) acc[i] = (f32x4){0.f, 0.f, 0.f, 0.f};

  if (mat == 0) {  // kt: acc[tt*2+et]
#pragma unroll
    for (int ks = 0; ks < 4; ++ks) {
      bf16x8 wf[2], xf[4];
#pragma unroll
      for (int et = 0; et < 2; ++et)
        wf[et] = *reinterpret_cast<const bf16x8*>(
            Wsrc + (ebase + et * 16 + lm) * DIM + ks * 32 + 8 * lg);
#pragma unroll
      for (int tt = 0; tt < 4; ++tt)
        xf[tt] = *reinterpret_cast<const bf16x8*>(
            &A[(tt * 16 + lm) * LDK + ks * 32 + 8 * lg]);
#pragma unroll
      for (int tt = 0; tt < 4; ++tt)
#pragma unroll
        for (int et = 0; et < 2; ++et)
          acc[tt * 2 + et] = __builtin_amdgcn_mfma_f32_16x16x32_bf16(
              xf[tt], wf[et], acc[tt * 2 + et], 0, 0, 0);
    }
  } else {  // vt: acc[et*4+tt]
#pragma unroll
    for (int ks = 0; ks < 4; ++ks) {
      bf16x8 wf[2], xf[4];
#pragma unroll
      for (int et = 0; et < 2; ++et)
        wf[et] = *reinterpret_cast<const bf16x8*>(
            Wsrc + (ebase + et * 16 + lm) * DIM + ks * 32 + 8 * lg);
#pragma unroll
      for (int tt = 0; tt < 4; ++tt)
        xf[tt] = *reinterpret_cast<const bf16x8*>(
            &A[(tt * 16 + lm) * LDK + ks * 32 + 8 * lg]);
#pragma unroll
      for (int et = 0; et < 2; ++et)
#pragma unroll
        for (int tt = 0; tt < 4; ++tt)
          acc[et * 4 + tt] = __builtin_amdgcn_mfma_f32_16x16x32_bf16(
              wf[et], xf[tt], acc[et * 4 + tt], 0, 0, 0);
    }
  }
  __syncthreads();  // x tile dead

  if (mat == 0) {
#pragma unroll
    for (int tt = 0; tt < 4; ++tt)
#pragma unroll
      for (int et = 0; et < 2; ++et)
#pragma unroll
        for (int r = 0; r < 4; ++r)
          A[(tt * 16 + 4 * lg + r) * LDK + ebase + et * 16 + lm] =
              f2bf(acc[tt * 2 + et][r]);
  } else {
#pragma unroll
    for (int et = 0; et < 2; ++et)
#pragma unroll
      for (int tt = 0; tt < 4; ++tt)
#pragma unroll
        for (int r = 0; r < 4; ++r)
          Bv[(ebase + et * 16 + 4 * lg + r) * 72 + tt * 16 + lm] =
              f2bf(acc[et * 4 + tt][r]);
  }
  __syncthreads();

  {  // combined coalesced copy-out (512 threads)
    size_t rowbase = (size_t)tg * BM;
#pragma unroll
    for (int u = 0; u < 2; ++u) {
      int i = u * 512 + t;
      int tok = i >> 4, off = (i & 15) * 8;
      ushort8_t vv = *reinterpret_cast<const ushort8_t*>(&A[tok * LDK + off]);
      *reinterpret_cast<ushort8_t*>(&kt[(rowbase + tok) * DIM + off]) = vv;
    }
    int bb = tg >> 6;
    int nb = (tg & 63) * BM;
#pragma unroll
    for (int u = 0; u < 2; ++u) {
      int i = u * 512 + t;
      int e = i >> 3, off = (i & 7) * 8;
      ushort8_t vv = *reinterpret_cast<const ushort8_t*>(&Bv[e * 72 + off]);
      *reinterpret_cast<ushort8_t*>(
          &vt[((size_t)bb * DIM + e) * NTOK + nb + off]) = vv;
    }
  }
}

// ---------------------------------------------------------------------------
// Kernel 3: attention partials. 256 threads (4 waves), block =
// (batch, 64-token chunk). grid = NB*ANCH = 2048 -> high blocks/CU.
// ---------------------------------------------------------------------------
__global__ __launch_bounds__(256, 4) void k_attn(
    const unsigned short* __restrict__ qbf, const unsigned short* __restrict__ kt,
    const unsigned short* __restrict__ vt, float* __restrict__ Np,
    float* __restrict__ Dp) {
  int bid = blockIdx.x;
  int b = bid >> 6, ch = bid & 63;
  int n0 = ch * ACHUNK;
  int t = threadIdx.x;
  int wid = t >> 6, l = t & 63, lm = l & 15, lg = l >> 4;

  __shared__ __align__(16) unsigned short a_lds[NSLOT][72];  // 1152 B

  {  // Phase 1: MFMA dots + softmax; wave wid -> tokens [wid*16, wid*16+16)
    const unsigned short* qb = qbf + (b * NSLOT + (lm & 7)) * DIM;
    bf16x8 aq[4];
#pragma unroll
    for (int ks = 0; ks < 4; ++ks)
      aq[ks] = *reinterpret_cast<const bf16x8*>(qb + ks * 32 + 8 * lg);
    const unsigned short* kb = kt + ((size_t)b * NTOK + n0) * DIM;
    int tok = wid * 16 + lm;
    f32x4 acc = (f32x4){0.f, 0.f, 0.f, 0.f};
#pragma unroll
    for (int ks = 0; ks < 4; ++ks) {
      bf16x8 bk = *reinterpret_cast<const bf16x8*>(
          kb + (size_t)tok * DIM + ks * 32 + 8 * lg);
      acc = __builtin_amdgcn_mfma_f32_16x16x32_bf16(aq[ks], bk, acc, 0, 0, 0);
    }
    float m4 = fmaxf(fmaxf(acc[0], acc[1]), fmaxf(acc[2], acc[3]));
    float m8 = fmaxf(m4, __shfl_xor(m4, 16));
    float e0 = expf(acc[0] - m8), e1 = expf(acc[1] - m8);
    float e2 = expf(acc[2] - m8), e3 = expf(acc[3] - m8);
    float s4 = e0 + e1 + e2 + e3;
    float s8 = s4 + __shfl_xor(s4, 16);
    float rs = 1.0f / s8;
    if (lg < 2) {
      a_lds[4 * lg + 0][tok] = f2bf(e0 * rs + ATT_EPS);
      a_lds[4 * lg + 1][tok] = f2bf(e1 * rs + ATT_EPS);
      a_lds[4 * lg + 2][tok] = f2bf(e2 * rs + ATT_EPS);
      a_lds[4 * lg + 3][tok] = f2bf(e3 * rs + ATT_EPS);
    }
  }
  __syncthreads();

  {  // Phase 2a: D partials; 2 slots per wave, half-wave reduce each
    int s = wid * 2 + (l >> 5), c = l & 31;
    float sm = bf2f(a_lds[s][c]) + bf2f(a_lds[s][c + 32]);
#pragma unroll
    for (int m = 16; m >= 1; m >>= 1) sm += __shfl_xor(sm, m);
    if (c == 0) Dp[(b * ANCH + ch) * NSLOT + s] = sm;
  }

  {  // Phase 2b: N partials via MFMA; wave wid owns d-tiles {2*wid, 2*wid+1}
#pragma unroll
    for (int dti = 0; dti < 2; ++dti) {
      int dt = wid * 2 + dti;
      f32x4 acc = (f32x4){0.f, 0.f, 0.f, 0.f};
      const unsigned short* vb =
          vt + ((size_t)b * DIM + dt * 16 + lm) * NTOK + n0;
#pragma unroll
      for (int kk = 0; kk < ACHUNK / 32; ++kk) {
        bf16x8 af = *reinterpret_cast<const bf16x8*>(
            &a_lds[lm & 7][kk * 32 + 8 * lg]);
        bf16x8 bv = *reinterpret_cast<const bf16x8*>(vb + kk * 32 + 8 * lg);
        acc = __builtin_amdgcn_mfma_f32_16x16x32_bf16(af, bv, acc, 0, 0, 0);
      }
      if (lg < 2) {
#pragma unroll
        for (int r = 0; r < 4; ++r)
          Np[((size_t)(b * ANCH + ch) * NSLOT + 4 * lg + r) * DIM + dt * 16 +
             lm] = acc[r];
      }
    }
  }
}

// ---------------------------------------------------------------------------
// Kernel 4: per (batch, slot): reduce partials -> GRU -> MLP -> slots;
// optional q tail (skipped on final iteration).
// ---------------------------------------------------------------------------
__global__ __launch_bounds__(256) void k_update(
    float* __restrict__ slots, unsigned short* __restrict__ qbf,
    const float* __restrict__ Np, const float* __restrict__ Dp,
    const float* __restrict__ W_ih, const float* __restrict__ W_hh,
    const float* __restrict__ b_ih, const float* __restrict__ b_hh,
    const float* __restrict__ W1, const float* __restrict__ b1,
    const float* __restrict__ W2, const float* __restrict__ b2,
    const float* __restrict__ lnfw, const float* __restrict__ lnfb,
    const float* __restrict__ Wq, const float* __restrict__ lnsw,
    const float* __restrict__ lnsb, int do_q) {
  int bs = blockIdx.x;
  int b = bs >> 3, s = bs & 7;
  int t = threadIdx.x;
  __shared__ __align__(16) float pn[2][DIM];
  __shared__ __align__(16) float upd[DIM];
  __shared__ __align__(16) float sprev[DIM];
  __shared__ __align__(16) float snew[DIM];
  __shared__ __align__(16) float ffin[DIM];
  __shared__ __align__(16) float ffb[DIM];
  __shared__ __align__(16) float gx[3 * DIM];
  __shared__ __align__(16) float gh[3 * DIM];

  float dsum = 0.0f;
  for (int ch = 0; ch < ANCH; ++ch) dsum += Dp[(b * ANCH + ch) * NSLOT + s];

  {  // 256 threads split the ANCH reduce into two halves
    int d = t & (DIM - 1), h = t >> 7;
    float a = 0.0f;
    for (int ch = h * (ANCH / 2); ch < (h + 1) * (ANCH / 2); ++ch)
      a += Np[((size_t)(b * ANCH + ch) * NSLOT + s) * DIM + d];
    pn[h][d] = a;
    if (h == 0) sprev[d] = slots[(b * NSLOT + s) * DIM + d];
  }
  __syncthreads();
  if (t < DIM) upd[t] = (pn[0][t] + pn[1][t]) / dsum;
  __syncthreads();

  for (int e = t; e < 3 * DIM; e += 256) {
    const float* wi = W_ih + e * DIM;
    const float* wh = W_hh + e * DIM;
    float ax = 0.0f, ah = 0.0f;
#pragma unroll
    for (int d4 = 0; d4 < DIM / 4; ++d4) {
      float4 u4 = *reinterpret_cast<const float4*>(&upd[d4 * 4]);
      float4 p4 = *reinterpret_cast<const float4*>(&sprev[d4 * 4]);
      float4 wi4 = *reinterpret_cast<const float4*>(wi + d4 * 4);
      float4 wh4 = *reinterpret_cast<const float4*>(wh + d4 * 4);
      ax += u4.x * wi4.x + u4.y * wi4.y + u4.z * wi4.z + u4.w * wi4.w;
      ah += p4.x * wh4.x + p4.y * wh4.y + p4.z * wh4.z + p4.w * wh4.w;
    }
    gx[e] = ax + b_ih[e];
    gh[e] = ah + b_hh[e];
  }
  __syncthreads();

  if (t < DIM) {
    float xr = gx[t], xz = gx[DIM + t], xn = gx[2 * DIM + t];
    float hr = gh[t], hz = gh[DIM + t], hn = gh[2 * DIM + t];
    float r = 1.0f / (1.0f + expf(-(xr + hr)));
    float z = 1.0f / (1.0f + expf(-(xz + hz)));
    float ng = tanhf(xn + r * hn);
    snew[t] = (1.0f - z) * ng + z * sprev[t];
  }
  __syncthreads();

  if (t < DIM) {  // LN_ff(snew) -> ffin
    float s1 = 0.0f, s2 = 0.0f;
#pragma unroll 8
    for (int d = 0; d < DIM; ++d) {
      float v = snew[d];
      s1 += v;
      s2 += v * v;
    }
    float mean = s1 * (1.0f / DIM);
    float var = fmaxf(s2 * (1.0f / DIM) - mean * mean, 0.0f);
    float inv = 1.0f / sqrtf(var + LN_EPS);
    ffin[t] = (snew[t] - mean) * inv * lnfw[t] + lnfb[t];
  }
  __syncthreads();

  if (t < DIM) {  // ff = relu(ffin @ W1^T + b1)
    const float* wr = W1 + t * DIM;
    float acc = 0.0f;
#pragma unroll
    for (int d4 = 0; d4 < DIM / 4; ++d4) {
      float4 f4 = *reinterpret_cast<const float4*>(&ffin[d4 * 4]);
      float4 w4 = *reinterpret_cast<const float4*>(wr + d4 * 4);
      acc += f4.x * w4.x + f4.y * w4.y + f4.z * w4.z + f4.w * w4.w;
    }
    ffb[t] = fmaxf(acc + b1[t], 0.0f);
  }
  __syncthreads();

  if (t < DIM) {  // final slots; stash for q tail
    const float* wr = W2 + t * DIM;
    float acc = 0.0f;
#pragma unroll
    for (int h4 = 0; h4 < DIM / 4; ++h4) {
      float4 f4 = *reinterpret_cast<const float4*>(&ffb[h4 * 4]);
      float4 w4 = *reinterpret_cast<const float4*>(wr + h4 * 4);
      acc += f4.x * w4.x + f4.y * w4.y + f4.z * w4.z + f4.w * w4.w;
    }
    float val = snew[t] + acc + b2[t];
    slots[(b * NSLOT + s) * DIM + t] = val;
    gx[t] = val;
  }
  if (!do_q) return;
  __syncthreads();

  if (t < DIM) {  // LN_s(final) -> gh
    float s1 = 0.0f, s2 = 0.0f;
#pragma unroll 8
    for (int d = 0; d < DIM; ++d) {
      float v = gx[d];
      s1 += v;
      s2 += v * v;
    }
    float mean = s1 * (1.0f / DIM);
    float var = fmaxf(s2 * (1.0f / DIM) - mean * mean, 0.0f);
    float inv = 1.0f / sqrtf(var + LN_EPS);
    gh[t] = (gx[t] - mean) * inv * lnsw[t] + lnsb[t];
  }
  __syncthreads();

  if (t < DIM) {  // q_next = SCALE * gh @ Wq^T
    const float* wr = Wq + t * DIM;
    float acc = 0.0f;
#pragma unroll
    for (int d4 = 0; d4 < DIM / 4; ++d4) {
      float4 g4 = *reinterpret_cast<const float4*>(&gh[d4 * 4]);
      float4 w4 = *reinterpret_cast<const float4*>(wr + d4 * 4);
      acc += g4.x * w4.x + g4.y * w4.y + g4.z * w4.z + g4.w * w4.w;
    }
    qbf[(b * NSLOT + s) * DIM + t] = f2bf(SCALE * acc);
  }
}

__global__ __launch_bounds__(256) void k_sentinel(float* __restrict__ out,
                                                  int n) {
  int i = blockIdx.x * blockDim.x + threadIdx.x;
  if (i < n) out[i] = 1234.5f;
}

// ---------------------------------------------------------------------------
extern "C" void kernel_launch(void* const* d_in, const int* in_sizes, int n_in,
                              void* d_out, int out_size, void* d_ws,
                              size_t ws_size, hipStream_t stream) {
  const float* inp = (const float*)d_in[0];
  const float* mu = (const float*)d_in[1];
  const float* lsig = (const float*)d_in[2];
  const float* Wq = (const float*)d_in[3];
  const float* Wk = (const float*)d_in[4];
  const float* Wv = (const float*)d_in[5];
  const float* W_ih = (const float*)d_in[6];
  const float* W_hh = (const float*)d_in[7];
  const float* b_ih = (const float*)d_in[8];
  const float* b_hh = (const float*)d_in[9];
  const float* W1 = (const float*)d_in[10];
  const float* b1 = (const float*)d_in[11];
  const float* W2 = (const float*)d_in[12];
  const float* b2 = (const float*)d_in[13];
  const float* ln_in_w = (const float*)d_in[14];
  const float* ln_in_b = (const float*)d_in[15];
  const float* ln_s_w = (const float*)d_in[16];
  const float* ln_s_b = (const float*)d_in[17];
  const float* ln_ff_w = (const float*)d_in[18];
  const float* ln_ff_b = (const float*)d_in[19];

  float* slots = (float*)d_out;

  // ws: kt bf16 | vt bf16 | Np f32 (ANCH=64) | Dp f32 | qbf bf16
  const size_t kv_elems = (size_t)NB * DIM * NTOK;           // 16.78M
  const size_t np_elems = (size_t)NB * ANCH * NSLOT * DIM;   // 2.097M
  const size_t dp_elems = (size_t)NB * ANCH * NSLOT;         // 16384
  const size_t q_elems = (size_t)NB * NSLOT * DIM;           // 32768
  size_t need = kv_elems * 2 * 2 + np_elems * 4 + dp_elems * 4 + q_elems * 2;
  if (ws_size < need) {
    k_sentinel<<<(out_size + 255) / 256, 256, 0, stream>>>((float*)d_out,
                                                           out_size);
    return;
  }
  char* wsb = (char*)d_ws;
  unsigned short* kt = (unsigned short*)wsb;
  unsigned short* vt = kt + kv_elems;
  float* Np = (float*)(wsb + kv_elems * 4);
  float* Dp = Np + np_elems;
  unsigned short* qbf = (unsigned short*)(Dp + dp_elems);
  // Wbf aliases Np (consumed by k_ln_kv before it0's k_attn overwrites Np)
  unsigned short* Wbf = (unsigned short*)Np;

  k_init_slots<<<NB, 256, 0, stream>>>(mu, lsig, slots, Wk, Wv, Wbf, Wq,
                                       ln_s_w, ln_s_b, qbf);
  k_ln_kv<<<NB * NTOK / BM, 512, 0, stream>>>(inp, Wbf, ln_in_w, ln_in_b, kt,
                                              vt);
  for (int it = 0; it < 3; ++it) {
    k_attn<<<NB * ANCH, 256, 0, stream>>>(qbf, kt, vt, Np, Dp);
    k_update<<<NB * NSLOT, 256, 0, stream>>>(slots, qbf, Np, Dp, W_ih, W_hh,
                                             b_ih, b_hh, W1, b1, W2, b2,
                                             ln_ff_w, ln_ff_b, Wq, ln_s_w,
                                             ln_s_b, it < 2 ? 1 : 0);
  }
}

// Round 16
// 181.518 us; speedup vs baseline: 1.0262x; 1.0262x over previous
//
#include <hip/hip_runtime.h>
#include <hip/hip_bf16.h>
#include <math.h>

#define DIM 128
#define NSLOT 8
#define NTOK 4096
#define NB 32
#define CHUNK 128
#define NCH (NTOK / CHUNK)   // 32
#define CHUNKPAD 136
#define LN_EPS 1e-3f
#define ATT_EPS 1e-8f
#define SCALE 0.08838834764831845f  // 128^-0.5

#define BM 64
#define LDK 136

typedef short bf16x8 __attribute__((ext_vector_type(8)));
typedef float f32x4 __attribute__((ext_vector_type(4)));
typedef unsigned short ushort8_t __attribute__((ext_vector_type(8)));

__device__ __forceinline__ float bf2f(unsigned short u) {
  return __uint_as_float(((unsigned)u) << 16);
}
__device__ __forceinline__ unsigned short f2bf(float f) {
  unsigned u = __float_as_uint(f);
  unsigned r = (u + 0x7FFFu + ((u >> 16) & 1u)) >> 16;
  return (unsigned short)r;
}

__device__ __forceinline__ float erfinv_like_xla(float x) {
  double xd = (double)x;
  double w = -log1p(-xd * xd);
  double p;
  if (w < 5.0) {
    w = w - 2.5;
    p = 2.81022636e-08;
    p = 3.43273939e-07 + p * w;
    p = -3.5233877e-06 + p * w;
    p = -4.39150654e-06 + p * w;
    p = 0.00021858087 + p * w;
    p = -0.00125372503 + p * w;
    p = -0.00417768164 + p * w;
    p = 0.246640727 + p * w;
    p = 1.50140941 + p * w;
  } else {
    w = sqrt(w) - 3.0;
    p = -0.000200214257;
    p = 0.000100950558 + p * w;
    p = 0.00134934322 + p * w;
    p = -0.00367342844 + p * w;
    p = 0.00573950773 + p * w;
    p = -0.0076224613 + p * w;
    p = 0.00943887047 + p * w;
    p = 1.00167406 + p * w;
    p = 2.83297682 + p * w;
  }
  return (float)(p * xd);
}

// ---------------------------------------------------------------------------
// Kernel 1: per-batch block: threefry slots init + weight bf16 casts + q0.
// Wbf: Wk|Wv (aliases Np, used only by k_ln_kv). Wubf: W_ih|W_hh|W1|W2
// (dedicated region, survives all iterations).
// ---------------------------------------------------------------------------
__global__ __launch_bounds__(256) void k_init_slots(
    const float* __restrict__ mu, const float* __restrict__ lsig,
    float* __restrict__ slots, const float* __restrict__ Wk,
    const float* __restrict__ Wv, unsigned short* __restrict__ Wbf,
    const float* __restrict__ W_ih, const float* __restrict__ W_hh,
    const float* __restrict__ W1, const float* __restrict__ W2,
    unsigned short* __restrict__ Wubf, const float* __restrict__ Wq,
    const float* __restrict__ lnw, const float* __restrict__ lnb,
    unsigned short* __restrict__ qbf) {
  int b = blockIdx.x, t = threadIdx.x;
  __shared__ __align__(16) float sc[NSLOT][DIM];
  __shared__ __align__(16) float sln[NSLOT][DIM];

#pragma unroll
  for (int u = 0; u < 2; ++u) {
    int i = b * 512 + u * 256 + t;
    Wbf[i] = f2bf(Wk[i]);
    Wbf[DIM * DIM + i] = f2bf(Wv[i]);
  }
#pragma unroll
  for (int u = 0; u < 16; ++u) {  // 8*D*D = 131072 elems over 32 blocks
    int i = b * 4096 + u * 256 + t;
    float v;
    if (i < 3 * DIM * DIM) v = W_ih[i];
    else if (i < 6 * DIM * DIM) v = W_hh[i - 3 * DIM * DIM];
    else if (i < 7 * DIM * DIM) v = W1[i - 6 * DIM * DIM];
    else v = W2[i - 7 * DIM * DIM];
    Wubf[i] = f2bf(v);
  }

#pragma unroll
  for (int r4 = 0; r4 < 4; ++r4) {
    int idx = b * 1024 + r4 * 256 + t;
    uint32_t x0 = 0u, x1 = (uint32_t)idx;
    uint32_t k0 = 0u, k1 = 42u;
    uint32_t ks[3] = {k0, k1, k0 ^ k1 ^ 0x1BD11BDAu};
    x0 += ks[0];
    x1 += ks[1];
    const int rot[2][4] = {{13, 15, 26, 6}, {17, 29, 16, 24}};
#pragma unroll
    for (int blk = 0; blk < 5; ++blk) {
      const int* r = rot[blk & 1];
#pragma unroll
      for (int j = 0; j < 4; ++j) {
        x0 += x1;
        x1 = (x1 << r[j]) | (x1 >> (32 - r[j]));
        x1 ^= x0;
      }
      x0 += ks[(blk + 1) % 3];
      x1 += ks[(blk + 2) % 3] + (uint32_t)(blk + 1);
    }
    uint32_t bits = x0 ^ x1;
    float f = __uint_as_float((bits >> 9) | 0x3F800000u) - 1.0f;
    const float mn = __uint_as_float(0xBF7FFFFFu);
    float u = fmaxf(f * 2.0f + mn, mn);
    float noise = 1.41421356f * erfinv_like_xla(u);
    int d = idx & (DIM - 1);
    float val = mu[d] + expf(lsig[d]) * noise;
    slots[idx] = val;
    int li = r4 * 256 + t;
    sc[li >> 7][li & (DIM - 1)] = val;
  }
  __syncthreads();

  {  // LN(slots) -> sln
    int s = t >> 5, c = t & 31;
    float4 xv = *reinterpret_cast<const float4*>(&sc[s][c * 4]);
    float ps = xv.x + xv.y + xv.z + xv.w;
    float pq = xv.x * xv.x + xv.y * xv.y + xv.z * xv.z + xv.w * xv.w;
#pragma unroll
    for (int m = 16; m >= 1; m >>= 1) {
      ps += __shfl_xor(ps, m, 32);
      pq += __shfl_xor(pq, m, 32);
    }
    float mean = ps * (1.0f / DIM);
    float var = fmaxf(pq * (1.0f / DIM) - mean * mean, 0.0f);
    float inv = 1.0f / sqrtf(var + LN_EPS);
    float vals[4] = {xv.x, xv.y, xv.z, xv.w};
#pragma unroll
    for (int ii = 0; ii < 4; ++ii) {
      int d = c * 4 + ii;
      sln[s][d] = (vals[ii] - mean) * inv * lnw[d] + lnb[d];
    }
  }
  __syncthreads();
  {  // q0 = SCALE * sln @ Wq^T
    int s = t >> 5, c = t & 31;
#pragma unroll
    for (int ii = 0; ii < 4; ++ii) {
      int e = c + 32 * ii;
      const float* wr = Wq + e * DIM;
      float acc = 0.0f;
#pragma unroll
      for (int d4 = 0; d4 < DIM / 4; ++d4) {
        float4 w4 = *reinterpret_cast<const float4*>(wr + d4 * 4);
        float4 s4 = *reinterpret_cast<const float4*>(&sln[s][d4 * 4]);
        acc += s4.x * w4.x + s4.y * w4.y + s4.z * w4.z + s4.w * w4.w;
      }
      qbf[(b * NSLOT + s) * DIM + e] = f2bf(SCALE * acc);
    }
  }
}

// ---------------------------------------------------------------------------
// Kernel 2: LN + MFMA projection. 512 threads / 8 waves, BM=64 tokens.
// ---------------------------------------------------------------------------
__global__ __launch_bounds__(512) void k_ln_kv(
    const float* __restrict__ inp, const unsigned short* __restrict__ Wbf,
    const float* __restrict__ lnw, const float* __restrict__ lnb,
    unsigned short* __restrict__ kt, unsigned short* __restrict__ vt) {
  __shared__ __align__(16) unsigned short A[BM * LDK];
  __shared__ __align__(16) unsigned short Bv[DIM * 72];
  int t = threadIdx.x;
  int tg = blockIdx.x;

  {
    int r = t >> 3, p = t & 7;
    const float* src = inp + ((size_t)tg * BM + r) * DIM + p * 16;
    float xr[16];
    float s = 0.f, sq = 0.f;
#pragma unroll
    for (int i4 = 0; i4 < 4; ++i4) {
      float4 v = *reinterpret_cast<const float4*>(src + i4 * 4);
      xr[i4 * 4 + 0] = v.x; xr[i4 * 4 + 1] = v.y;
      xr[i4 * 4 + 2] = v.z; xr[i4 * 4 + 3] = v.w;
      s += v.x + v.y + v.z + v.w;
      sq += v.x * v.x + v.y * v.y + v.z * v.z + v.w * v.w;
    }
    s += __shfl_xor(s, 1); sq += __shfl_xor(sq, 1);
    s += __shfl_xor(s, 2); sq += __shfl_xor(sq, 2);
    s += __shfl_xor(s, 4); sq += __shfl_xor(sq, 4);
    float mean = s * (1.0f / DIM);
    float var = fmaxf(sq * (1.0f / DIM) - mean * mean, 0.0f);
    float inv = 1.0f / sqrtf(var + LN_EPS);
#pragma unroll
    for (int c8 = 0; c8 < 2; ++c8) {
      ushort8_t pk;
#pragma unroll
      for (int j = 0; j < 8; ++j) {
        int d = p * 16 + c8 * 8 + j;
        float y = (xr[c8 * 8 + j] - mean) * inv * lnw[d] + lnb[d];
        pk[j] = f2bf(y);
      }
      *reinterpret_cast<ushort8_t*>(&A[r * LDK + p * 16 + c8 * 8]) = pk;
    }
  }
  __syncthreads();

  int w = t >> 6, l = t & 63, lm = l & 15, lg = l >> 4;
  int mat = w >> 2;
  int ebase = (w & 3) * 32;
  const unsigned short* Wsrc = Wbf + mat * DIM * DIM;

  f32x4 acc[8];
#pragma unroll
  for (int i = 0; i < 8; ++i) acc[i] = (f32x4){0.f, 0.f, 0.f, 0.f};

  if (mat == 0) {
#pragma unroll
    for (int ks = 0; ks < 4; ++ks) {
      bf16x8 wf[2], xf[4];
#pragma unroll
      for (int et = 0; et < 2; ++et)
        wf[et] = *reinterpret_cast<const bf16x8*>(
            Wsrc + (ebase + et * 16 + lm) * DIM + ks * 32 + 8 * lg);
#pragma unroll
      for (int tt = 0; tt < 4; ++tt)
        xf[tt] = *reinterpret_cast<const bf16x8*>(
            &A[(tt * 16 + lm) * LDK + ks * 32 + 8 * lg]);
#pragma unroll
      for (int tt = 0; tt < 4; ++tt)
#pragma unroll
        for (int et = 0; et < 2; ++et)
          acc[tt * 2 + et] = __builtin_amdgcn_mfma_f32_16x16x32_bf16(
              xf[tt], wf[et], acc[tt * 2 + et], 0, 0, 0);
    }
  } else {
#pragma unroll
    for (int ks = 0; ks < 4; ++ks) {
      bf16x8 wf[2], xf[4];
#pragma unroll
      for (int et = 0; et < 2; ++et)
        wf[et] = *reinterpret_cast<const bf16x8*>(
            Wsrc + (ebase + et * 16 + lm) * DIM + ks * 32 + 8 * lg);
#pragma unroll
      for (int tt = 0; tt < 4; ++tt)
        xf[tt] = *reinterpret_cast<const bf16x8*>(
            &A[(tt * 16 + lm) * LDK + ks * 32 + 8 * lg]);
#pragma unroll
      for (int et = 0; et < 2; ++et)
#pragma unroll
        for (int tt = 0; tt < 4; ++tt)
          acc[et * 4 + tt] = __builtin_amdgcn_mfma_f32_16x16x32_bf16(
              wf[et], xf[tt], acc[et * 4 + tt], 0, 0, 0);
    }
  }
  __syncthreads();

  if (mat == 0) {
#pragma unroll
    for (int tt = 0; tt < 4; ++tt)
#pragma unroll
      for (int et = 0; et < 2; ++et)
#pragma unroll
        for (int r = 0; r < 4; ++r)
          A[(tt * 16 + 4 * lg + r) * LDK + ebase + et * 16 + lm] =
              f2bf(acc[tt * 2 + et][r]);
  } else {
#pragma unroll
    for (int et = 0; et < 2; ++et)
#pragma unroll
      for (int tt = 0; tt < 4; ++tt)
#pragma unroll
        for (int r = 0; r < 4; ++r)
          Bv[(ebase + et * 16 + 4 * lg + r) * 72 + tt * 16 + lm] =
              f2bf(acc[et * 4 + tt][r]);
  }
  __syncthreads();

  {
    size_t rowbase = (size_t)tg * BM;
#pragma unroll
    for (int u = 0; u < 2; ++u) {
      int i = u * 512 + t;
      int tok = i >> 4, off = (i & 15) * 8;
      ushort8_t vv = *reinterpret_cast<const ushort8_t*>(&A[tok * LDK + off]);
      *reinterpret_cast<ushort8_t*>(&kt[(rowbase + tok) * DIM + off]) = vv;
    }
    int bb = tg >> 6;
    int nb = (tg & 63) * BM;
#pragma unroll
    for (int u = 0; u < 2; ++u) {
      int i = u * 512 + t;
      int e = i >> 3, off = (i & 7) * 8;
      ushort8_t vv = *reinterpret_cast<const ushort8_t*>(&Bv[e * 72 + off]);
      *reinterpret_cast<ushort8_t*>(
          &vt[((size_t)bb * DIM + e) * NTOK + nb + off]) = vv;
    }
  }
}

// ---------------------------------------------------------------------------
// Kernel 3: attention partials. 512 threads, (batch, 128-token chunk).
// ---------------------------------------------------------------------------
__global__ __launch_bounds__(512, 4) void k_attn(
    const unsigned short* __restrict__ qbf, const unsigned short* __restrict__ kt,
    const unsigned short* __restrict__ vt, float* __restrict__ Np,
    float* __restrict__ Dp) {
  int bid = blockIdx.x;
  int b = bid >> 5, ch = bid & 31;
  int n0 = ch * CHUNK;
  int t = threadIdx.x;
  int wid = t >> 6, l = t & 63, lm = l & 15, lg = l >> 4;

  __shared__ __align__(16) unsigned short a_lds[NSLOT][CHUNKPAD];

  {  // Phase 1: MFMA dots + softmax over slots -> a_lds bf16 [slot][tok]
    const unsigned short* qb = qbf + (b * NSLOT + (lm & 7)) * DIM;
    bf16x8 aq[4];
#pragma unroll
    for (int ks = 0; ks < 4; ++ks)
      aq[ks] = *reinterpret_cast<const bf16x8*>(qb + ks * 32 + 8 * lg);
    const unsigned short* kb = kt + ((size_t)b * NTOK + n0) * DIM;
    int tok = wid * 16 + lm;
    f32x4 acc = (f32x4){0.f, 0.f, 0.f, 0.f};
#pragma unroll
    for (int ks = 0; ks < 4; ++ks) {
      bf16x8 bk = *reinterpret_cast<const bf16x8*>(
          kb + (size_t)tok * DIM + ks * 32 + 8 * lg);
      acc = __builtin_amdgcn_mfma_f32_16x16x32_bf16(aq[ks], bk, acc, 0, 0, 0);
    }
    float m4 = fmaxf(fmaxf(acc[0], acc[1]), fmaxf(acc[2], acc[3]));
    float m8 = fmaxf(m4, __shfl_xor(m4, 16));
    float e0 = expf(acc[0] - m8), e1 = expf(acc[1] - m8);
    float e2 = expf(acc[2] - m8), e3 = expf(acc[3] - m8);
    float s4 = e0 + e1 + e2 + e3;
    float s8 = s4 + __shfl_xor(s4, 16);
    float rs = 1.0f / s8;
    if (lg < 2) {
      a_lds[4 * lg + 0][tok] = f2bf(e0 * rs + ATT_EPS);
      a_lds[4 * lg + 1][tok] = f2bf(e1 * rs + ATT_EPS);
      a_lds[4 * lg + 2][tok] = f2bf(e2 * rs + ATT_EPS);
      a_lds[4 * lg + 3][tok] = f2bf(e3 * rs + ATT_EPS);
    }
  }
  __syncthreads();

  {  // Phase 2a: D partials; wave = slot, 64-lane reduce
    float s = 0.0f;
#pragma unroll
    for (int jj = 0; jj < CHUNK / 64; ++jj) s += bf2f(a_lds[wid][l + 64 * jj]);
#pragma unroll
    for (int m = 32; m >= 1; m >>= 1) s += __shfl_xor(s, m);
    if (l == 0) Dp[(b * NCH + ch) * NSLOT + wid] = s;
  }

  {  // Phase 2b: N partials via MFMA; wave wid owns d-tile [16*wid,16*wid+16)
    f32x4 acc = (f32x4){0.f, 0.f, 0.f, 0.f};
    const unsigned short* vb =
        vt + ((size_t)b * DIM + wid * 16 + lm) * NTOK + n0;
#pragma unroll
    for (int kk = 0; kk < CHUNK / 32; ++kk) {
      bf16x8 af = *reinterpret_cast<const bf16x8*>(
          &a_lds[lm & 7][kk * 32 + 8 * lg]);
      bf16x8 bv = *reinterpret_cast<const bf16x8*>(vb + kk * 32 + 8 * lg);
      acc = __builtin_amdgcn_mfma_f32_16x16x32_bf16(af, bv, acc, 0, 0, 0);
    }
    if (lg < 2) {
#pragma unroll
      for (int r = 0; r < 4; ++r)
        Np[((size_t)(b * NCH + ch) * NSLOT + 4 * lg + r) * DIM + wid * 16 +
           lm] = acc[r];
    }
  }
}

// ---------------------------------------------------------------------------
// Kernel 4: per (batch, slot): reduce partials -> GRU -> MLP -> slots;
// bf16 weights from Wubf; optional q tail.
// ---------------------------------------------------------------------------
__global__ __launch_bounds__(256) void k_update(
    float* __restrict__ slots, unsigned short* __restrict__ qbf,
    const float* __restrict__ Np, const float* __restrict__ Dp,
    const unsigned short* __restrict__ Wubf, const float* __restrict__ b_ih,
    const float* __restrict__ b_hh, const float* __restrict__ b1,
    const float* __restrict__ b2, const float* __restrict__ lnfw,
    const float* __restrict__ lnfb, const float* __restrict__ Wq,
    const float* __restrict__ lnsw, const float* __restrict__ lnsb,
    int do_q) {
  int bs = blockIdx.x;
  int b = bs >> 3, s = bs & 7;
  int t = threadIdx.x;
  __shared__ __align__(16) float pn[2][DIM];
  __shared__ __align__(16) float upd[DIM];
  __shared__ __align__(16) float sprev[DIM];
  __shared__ __align__(16) float snew[DIM];
  __shared__ __align__(16) float ffin[DIM];
  __shared__ __align__(16) float ffb[DIM];
  __shared__ __align__(16) float gx[3 * DIM];
  __shared__ __align__(16) float gh[3 * DIM];

  const unsigned short* Wih = Wubf;
  const unsigned short* Whh = Wubf + 3 * DIM * DIM;
  const unsigned short* W1b = Wubf + 6 * DIM * DIM;
  const unsigned short* W2b = Wubf + 7 * DIM * DIM;

  float dsum = 0.0f;
  for (int ch = 0; ch < NCH; ++ch) dsum += Dp[(b * NCH + ch) * NSLOT + s];

  {  // 256 threads split the NCH reduce into two halves
    int d = t & (DIM - 1), h = t >> 7;
    float a = 0.0f;
    for (int ch = h * (NCH / 2); ch < (h + 1) * (NCH / 2); ++ch)
      a += Np[((size_t)(b * NCH + ch) * NSLOT + s) * DIM + d];
    pn[h][d] = a;
    if (h == 0) sprev[d] = slots[(b * NSLOT + s) * DIM + d];
  }
  __syncthreads();
  if (t < DIM) upd[t] = (pn[0][t] + pn[1][t]) / dsum;
  __syncthreads();

  for (int e = t; e < 3 * DIM; e += 256) {
    const unsigned short* wi = Wih + e * DIM;
    const unsigned short* wh = Whh + e * DIM;
    float ax = 0.0f, ah = 0.0f;
#pragma unroll
    for (int d8 = 0; d8 < DIM / 8; ++d8) {
      ushort8_t wi8 = *reinterpret_cast<const ushort8_t*>(wi + d8 * 8);
      ushort8_t wh8 = *reinterpret_cast<const ushort8_t*>(wh + d8 * 8);
#pragma unroll
      for (int j = 0; j < 8; ++j) {
        float uv = upd[d8 * 8 + j], pv = sprev[d8 * 8 + j];
        ax += uv * bf2f(wi8[j]);
        ah += pv * bf2f(wh8[j]);
      }
    }
    gx[e] = ax + b_ih[e];
    gh[e] = ah + b_hh[e];
  }
  __syncthreads();

  if (t < DIM) {
    float xr = gx[t], xz = gx[DIM + t], xn = gx[2 * DIM + t];
    float hr = gh[t], hz = gh[DIM + t], hn = gh[2 * DIM + t];
    float r = 1.0f / (1.0f + expf(-(xr + hr)));
    float z = 1.0f / (1.0f + expf(-(xz + hz)));
    float ng = tanhf(xn + r * hn);
    snew[t] = (1.0f - z) * ng + z * sprev[t];
  }
  __syncthreads();

  if (t < DIM) {  // LN_ff(snew) -> ffin
    float s1 = 0.0f, s2 = 0.0f;
#pragma unroll 8
    for (int d = 0; d < DIM; ++d) {
      float v = snew[d];
      s1 += v;
      s2 += v * v;
    }
    float mean = s1 * (1.0f / DIM);
    float var = fmaxf(s2 * (1.0f / DIM) - mean * mean, 0.0f);
    float inv = 1.0f / sqrtf(var + LN_EPS);
    ffin[t] = (snew[t] - mean) * inv * lnfw[t] + lnfb[t];
  }
  __syncthreads();

  if (t < DIM) {  // ff = relu(ffin @ W1^T + b1)
    const unsigned short* wr = W1b + t * DIM;
    float acc = 0.0f;
#pragma unroll
    for (int d8 = 0; d8 < DIM / 8; ++d8) {
      ushort8_t w8 = *reinterpret_cast<const ushort8_t*>(wr + d8 * 8);
#pragma unroll
      for (int j = 0; j < 8; ++j) acc += ffin[d8 * 8 + j] * bf2f(w8[j]);
    }
    ffb[t] = fmaxf(acc + b1[t], 0.0f);
  }
  __syncthreads();

  if (t < DIM) {  // final slots; stash for q tail
    const unsigned short* wr = W2b + t * DIM;
    float acc = 0.0f;
#pragma unroll
    for (int h8 = 0; h8 < DIM / 8; ++h8) {
      ushort8_t w8 = *reinterpret_cast<const ushort8_t*>(wr + h8 * 8);
#pragma unroll
      for (int j = 0; j < 8; ++j) acc += ffb[h8 * 8 + j] * bf2f(w8[j]);
    }
    float val = snew[t] + acc + b2[t];
    slots[(b * NSLOT + s) * DIM + t] = val;
    gx[t] = val;
  }
  if (!do_q) return;
  __syncthreads();

  if (t < DIM) {  // LN_s(final) -> gh
    float s1 = 0.0f, s2 = 0.0f;
#pragma unroll 8
    for (int d = 0; d < DIM; ++d) {
      float v = gx[d];
      s1 += v;
      s2 += v * v;
    }
    float mean = s1 * (1.0f / DIM);
    float var = fmaxf(s2 * (1.0f / DIM) - mean * mean, 0.0f);
    float inv = 1.0f / sqrtf(var + LN_EPS);
    gh[t] = (gx[t] - mean) * inv * lnsw[t] + lnsb[t];
  }
  __syncthreads();

  if (t < DIM) {  // q_next = SCALE * gh @ Wq^T
    const float* wr = Wq + t * DIM;
    float acc = 0.0f;
#pragma unroll
    for (int d4 = 0; d4 < DIM / 4; ++d4) {
      float4 g4 = *reinterpret_cast<const float4*>(&gh[d4 * 4]);
      float4 w4 = *reinterpret_cast<const float4*>(wr + d4 * 4);
      acc += g4.x * w4.x + g4.y * w4.y + g4.z * w4.z + g4.w * w4.w;
    }
    qbf[(b * NSLOT + s) * DIM + t] = f2bf(SCALE * acc);
  }
}

__global__ __launch_bounds__(256) void k_sentinel(float* __restrict__ out,
                                                  int n) {
  int i = blockIdx.x * blockDim.x + threadIdx.x;
  if (i < n) out[i] = 1234.5f;
}

// ---------------------------------------------------------------------------
extern "C" void kernel_launch(void* const* d_in, const int* in_sizes, int n_in,
                              void* d_out, int out_size, void* d_ws,
                              size_t ws_size, hipStream_t stream) {
  const float* inp = (const float*)d_in[0];
  const float* mu = (const float*)d_in[1];
  const float* lsig = (const float*)d_in[2];
  const float* Wq = (const float*)d_in[3];
  const float* Wk = (const float*)d_in[4];
  const float* Wv = (const float*)d_in[5];
  const float* W_ih = (const float*)d_in[6];
  const float* W_hh = (const float*)d_in[7];
  const float* b_ih = (const float*)d_in[8];
  const float* b_hh = (const float*)d_in[9];
  const float* W1 = (const float*)d_in[10];
  const float* b1 = (const float*)d_in[11];
  const float* W2 = (const float*)d_in[12];
  const float* b2 = (const float*)d_in[13];
  const float* ln_in_w = (const float*)d_in[14];
  const float* ln_in_b = (const float*)d_in[15];
  const float* ln_s_w = (const float*)d_in[16];
  const float* ln_s_b = (const float*)d_in[17];
  const float* ln_ff_w = (const float*)d_in[18];
  const float* ln_ff_b = (const float*)d_in[19];

  float* slots = (float*)d_out;

  // ws: kt bf16 | vt bf16 | Np f32 | Dp f32 | qbf bf16 | Wubf bf16
  const size_t kv_elems = (size_t)NB * DIM * NTOK;          // 16.78M
  const size_t np_elems = (size_t)NB * NCH * NSLOT * DIM;   // 1048576
  const size_t dp_elems = (size_t)NB * NCH * NSLOT;         // 8192
  const size_t q_elems = (size_t)NB * NSLOT * DIM;          // 32768
  const size_t wu_elems = (size_t)8 * DIM * DIM;            // 131072
  size_t need = kv_elems * 2 * 2 + np_elems * 4 + dp_elems * 4 + q_elems * 2 +
                wu_elems * 2;
  if (ws_size < need) {
    k_sentinel<<<(out_size + 255) / 256, 256, 0, stream>>>((float*)d_out,
                                                           out_size);
    return;
  }
  char* wsb = (char*)d_ws;
  unsigned short* kt = (unsigned short*)wsb;
  unsigned short* vt = kt + kv_elems;
  float* Np = (float*)(wsb + kv_elems * 4);
  float* Dp = Np + np_elems;
  unsigned short* qbf = (unsigned short*)(Dp + dp_elems);
  unsigned short* Wubf = qbf + q_elems;
  // Wbf (k/v proj weights) aliases Np: consumed by k_ln_kv before attn it0
  unsigned short* Wbf = (unsigned short*)Np;

  k_init_slots<<<NB, 256, 0, stream>>>(mu, lsig, slots, Wk, Wv, Wbf, W_ih,
                                       W_hh, W1, W2, Wubf, Wq, ln_s_w, ln_s_b,
                                       qbf);
  k_ln_kv<<<NB * NTOK / BM, 512, 0, stream>>>(inp, Wbf, ln_in_w, ln_in_b, kt,
                                              vt);
  for (int it = 0; it < 3; ++it) {
    k_attn<<<NB * NCH, 512, 0, stream>>>(qbf, kt, vt, Np, Dp);
    k_update<<<NB * NSLOT, 256, 0, stream>>>(slots, qbf, Np, Dp, Wubf, b_ih,
                                             b_hh, b1, b2, ln_ff_w, ln_ff_b,
                                             Wq, ln_s_w, ln_s_b,
                                             it < 2 ? 1 : 0);
  }
}